// Round 6
// baseline (225.802 us; speedup 1.0000x reference)
//
#include <hip/hip_runtime.h>
#include <hip/hip_bf16.h>
#include <float.h>
#include <math.h>

// Problem constants (from reference)
#define N 8192
#define D 2048
#define CS 8        // CHUNK_SIZE
#define NT 64       // N / BN column tiles

// GEMM tiling (fp8: BK=128 bytes per row per tile)
#define BM 128
#define BN 128
#define BK 128
#define GP 1040     // padded row-group pitch: 1024 data + 16 pad (bank shift)

typedef __attribute__((ext_vector_type(4))) int   i32x4;
typedef __attribute__((ext_vector_type(8))) int   i32x8;
typedef __attribute__((ext_vector_type(4))) float f32x4;
typedef __attribute__((ext_vector_type(2))) float f32x2;

__device__ __forceinline__ void g2l16(const void* g, void* l) {
    __builtin_amdgcn_global_load_lds(
        (const __attribute__((address_space(1))) void*)g,
        (__attribute__((address_space(3))) void*)l, 16, 0, 0);
}

// Kernel 1: per chunk of 8 rows — one read of x produces:
//   fp8(e4m3) quantization of the 8 rows, and d_ap[row] (fp32 exact).
__global__ __launch_bounds__(256) void chunk_kernel(
    const float* __restrict__ x, int* __restrict__ xq, float* __restrict__ d_ap) {
    const int c = blockIdx.x;
    const int tid = threadIdx.x;
    const float4* xr4 = (const float4*)(x + (size_t)c * CS * D);

    float dap[CS];
    #pragma unroll
    for (int r = 0; r < CS; ++r) dap[r] = 0.f;

    #pragma unroll
    for (int h = 0; h < 2; ++h) {
        const int col = h * 256 + tid;          // float4 index in row (0..511)
        float4 v[CS];
        float4 cen = make_float4(0, 0, 0, 0);
        #pragma unroll
        for (int r = 0; r < CS; ++r) {
            v[r] = xr4[r * 512 + col];
            cen.x += v[r].x; cen.y += v[r].y; cen.z += v[r].z; cen.w += v[r].w;
        }
        cen.x *= 0.125f; cen.y *= 0.125f; cen.z *= 0.125f; cen.w *= 0.125f;
        #pragma unroll
        for (int r = 0; r < CS; ++r) {
            int p = __builtin_amdgcn_cvt_pk_fp8_f32(v[r].x, v[r].y, 0, false);
            p     = __builtin_amdgcn_cvt_pk_fp8_f32(v[r].z, v[r].w, p, true);
            xq[(size_t)(c * CS + r) * 512 + col] = p;
            dap[r] += fabsf(v[r].x - cen.x) + fabsf(v[r].y - cen.y)
                    + fabsf(v[r].z - cen.z) + fabsf(v[r].w - cen.w);
        }
    }
    #pragma unroll
    for (int r = 0; r < CS; ++r)
        #pragma unroll
        for (int m = 1; m <= 32; m <<= 1) dap[r] += __shfl_xor(dap[r], m, 64);

    __shared__ float sred[CS][4];
    const int lane = tid & 63, wave = tid >> 6;
    if (lane == 0)
        #pragma unroll
        for (int r = 0; r < CS; ++r) sred[r][wave] = dap[r];
    __syncthreads();
    if (tid < CS) {
        const float s = sred[tid][0] + sred[tid][1] + sred[tid][2] + sred[tid][3];
        d_ap[c * CS + tid] = 0.5f * s / (float)D;   // |x-x_pos| = 0.5|x-center|
    }
}

// Kernel 2: fp8 MX-MFMA GEMM sim = Xq*Xq^T over the UPPER TRIANGLE of 128x128
// tiles, scales pinned to 1.0. Identity segment swizzle (R4's known-good global
// pattern: logical seg l of row r stored at physical l^(r&7)); bank conflicts
// fixed by +16B pad per 1KB row-group in LDS (each g2l16 = one row-group).
__global__ __launch_bounds__(256, 3) void gemm_argmax_kernel(
    const char* __restrict__ xq,
    float* __restrict__ pmax, int* __restrict__ pidx) {
    __shared__ __align__(16) char sA[16 * GP];   // 16.25 KB
    __shared__ __align__(16) char sB[16 * GP];   // 16.25 KB

    // Triangular decode: Start(r) = r*(129-r)/2, t in [0, 2080)
    const int t = blockIdx.x;
    int bi = (int)((129.0 - sqrt((double)(129 * 129 - 8 * t))) * 0.5);
    if (bi > 63) bi = 63;
    if (bi < 0) bi = 0;
    while ((bi + 1) * (129 - (bi + 1)) / 2 <= t) ++bi;
    while (bi * (129 - bi) / 2 > t) --bi;
    const int bj = bi + (t - bi * (129 - bi) / 2);
    const bool diag = (bi == bj);

    const int tid  = threadIdx.x;
    const int lane = tid & 63;
    const int wave = tid >> 6;
    const int quad = lane >> 4;
    const int l15  = lane & 15;

    const int i0 = bi * BM;
    const int j0 = bj * BN;
    const int wr = (wave >> 1) * 64;   // wave row offset in tile
    const int wc = (wave & 1) * 64;    // wave col offset in tile

    // LDS read offsets (bytes), K-loop invariant. Lane needs logical segs
    // {2q, 2q+1} of its row: phys = (2q)^(r&7) and phys^1 (= +/-16 B, sign by
    // row parity since the group pad breaks the plain ^16 identity).
    int aoff0[4], aoff1[4], boff0[4], boff1[4];
    #pragma unroll
    for (int tt = 0; tt < 4; ++tt) {
        const int arow = wr + tt * 16 + l15;
        aoff0[tt] = (arow >> 3) * GP + (arow & 7) * 128 + (((2 * quad) ^ (arow & 7)) << 4);
        aoff1[tt] = aoff0[tt] + ((arow & 1) ? -16 : 16);
        const int brow = wc + tt * 16 + l15;
        boff0[tt] = (brow >> 3) * GP + (brow & 7) * 128 + (((2 * quad) ^ (brow & 7)) << 4);
        boff1[tt] = boff0[tt] + ((brow & 1) ? -16 : 16);
    }
    // Staging: each g2l16 writes one 8-row group (64 lanes x 16B = 1024B) at
    // group base g*GP. Global side identical to R4 (identity swizzle).
    const char* gsrcA[4]; const char* gsrcB[4];
    char* ldstA[4]; char* ldstB[4];
    #pragma unroll
    for (int c = 0; c < 4; ++c) {
        const int g   = wave + 4 * c;               // row-group 0..15
        const int row = g * 8 + (lane >> 3);
        const int pc  = lane & 7;
        const int gk  = (pc ^ (lane >> 3)) << 4;    // logical seg at phys pc
        gsrcA[c] = xq + (size_t)(i0 + row) * D + gk;
        gsrcB[c] = xq + (size_t)(j0 + row) * D + gk;
        ldstA[c] = sA + g * GP;
        ldstB[c] = sB + g * GP;
    }

    f32x4 acc[4][4] = {};

    for (int kk = 0; kk < D; kk += BK) {
        #pragma unroll
        for (int c = 0; c < 4; ++c) { g2l16(gsrcA[c], ldstA[c]); g2l16(gsrcB[c], ldstB[c]); }
        #pragma unroll
        for (int c = 0; c < 4; ++c) { gsrcA[c] += BK; gsrcB[c] += BK; }
        __syncthreads();

        i32x8 af[4], bfr[4];
        #pragma unroll
        for (int tt = 0; tt < 4; ++tt) {
            const i32x4 alo = *(const i32x4*)(sA + aoff0[tt]);
            const i32x4 ahi = *(const i32x4*)(sA + aoff1[tt]);
            const i32x4 blo = *(const i32x4*)(sB + boff0[tt]);
            const i32x4 bhi = *(const i32x4*)(sB + boff1[tt]);
            #pragma unroll
            for (int e = 0; e < 4; ++e) {
                af[tt][e] = alo[e];  af[tt][e + 4] = ahi[e];
                bfr[tt][e] = blo[e]; bfr[tt][e + 4] = bhi[e];
            }
        }
        #pragma unroll
        for (int ti = 0; ti < 4; ++ti)
            #pragma unroll
            for (int tj = 0; tj < 4; ++tj)
                acc[ti][tj] = __builtin_amdgcn_mfma_scale_f32_16x16x128_f8f6f4(
                    af[ti], bfr[tj], acc[ti][tj],
                    0, 0,                    // cbsz=fp8(e4m3), blgp=fp8(e4m3)
                    0, 0x7F7F7F7F,           // opsel_a, scale_a = 1.0
                    0, 0x7F7F7F7F);          // opsel_b, scale_b = 1.0
        __syncthreads();
    }

    // Epilogue. C/D layout (shape-determined): col = lane&15, row = quad*4 + reg.
    float* rmax = (float*)(sA + 0);      // [128][2]
    int*   ridx = (int*)  (sA + 1024);   // [128][2]
    float* cmax = (float*)(sA + 2048);   // [128][2]
    int*   cidx = (int*)  (sA + 3072);   // [128][2]

    // --- row side: per C row, argmax over this wave's 64 cols ---
    #pragma unroll
    for (int ti = 0; ti < 4; ++ti) {
        #pragma unroll
        for (int r = 0; r < 4; ++r) {
            const int li = wr + ti * 16 + quad * 4 + r;
            const int gi = i0 + li;
            float bv = -FLT_MAX; int bj_ = 0x7fffffff;
            #pragma unroll
            for (int tj = 0; tj < 4; ++tj) {
                const int gj = j0 + wc + tj * 16 + l15;
                const float vv = acc[ti][tj][r];
                const bool ok = !diag || ((gi >> 2) != (gj >> 2));
                if (ok && (vv > bv || (vv == bv && gj < bj_))) { bv = vv; bj_ = gj; }
            }
            #pragma unroll
            for (int m = 1; m <= 8; m <<= 1) {
                const float ov = __shfl_xor(bv, m, 64);
                const int   oj = __shfl_xor(bj_, m, 64);
                if (ov > bv || (ov == bv && oj < bj_)) { bv = ov; bj_ = oj; }
            }
            if (l15 == 0) { rmax[li * 2 + (wave & 1)] = bv; ridx[li * 2 + (wave & 1)] = bj_; }
        }
    }

    // --- col side (off-diagonal only): per C col, argmax over wave's 64 rows ---
    if (!diag) {
        #pragma unroll
        for (int tj = 0; tj < 4; ++tj) {
            float bv = -FLT_MAX; int bi_ = 0x7fffffff;
            #pragma unroll
            for (int ti = 0; ti < 4; ++ti)
                #pragma unroll
                for (int r = 0; r < 4; ++r) {
                    const int gi = i0 + wr + ti * 16 + quad * 4 + r;
                    const float vv = acc[ti][tj][r];
                    if (vv > bv || (vv == bv && gi < bi_)) { bv = vv; bi_ = gi; }
                }
            #pragma unroll
            for (int m = 16; m <= 32; m <<= 1) {   // reduce across quads
                const float ov = __shfl_xor(bv, m, 64);
                const int   oi = __shfl_xor(bi_, m, 64);
                if (ov > bv || (ov == bv && oi < bi_)) { bv = ov; bi_ = oi; }
            }
            if (quad == 0) {
                const int cj = wc + tj * 16 + l15;
                cmax[cj * 2 + (wave >> 1)] = bv; cidx[cj * 2 + (wave >> 1)] = bi_;
            }
        }
    }
    __syncthreads();

    if (tid < BM) {
        const float v0 = rmax[tid * 2], v1 = rmax[tid * 2 + 1];
        const int   a0 = ridx[tid * 2], a1 = ridx[tid * 2 + 1];
        float bv; int ba;
        if (v1 > v0 || (v1 == v0 && a1 < a0)) { bv = v1; ba = a1; }
        else                                  { bv = v0; ba = a0; }
        pmax[(size_t)(i0 + tid) * NT + bj] = bv;
        pidx[(size_t)(i0 + tid) * NT + bj] = ba;
    } else if (!diag) {
        const int c = tid - BM;
        const float v0 = cmax[c * 2], v1 = cmax[c * 2 + 1];
        const int   a0 = cidx[c * 2], a1 = cidx[c * 2 + 1];
        float bv; int ba;
        if (v1 > v0 || (v1 == v0 && a1 < a0)) { bv = v1; ba = a1; }
        else                                  { bv = v0; ba = a0; }
        pmax[(size_t)(j0 + c) * NT + bi] = bv;
        pidx[(size_t)(j0 + c) * NT + bi] = ba;
    }
}

// Kernel 3: per row — reduce 64 partials to neg_idx; d_an from fp8 xq (L3-hot).
__global__ __launch_bounds__(256) void neg_kernel(
    const int* __restrict__ xq, const float* __restrict__ d_ap,
    const float* __restrict__ pmax, const int* __restrict__ pidx,
    float* __restrict__ term) {
    const int i = blockIdx.x;
    const int tid = threadIdx.x;
    __shared__ int s_neg;
    __shared__ float red[4];

    if (tid < 64) {
        float bv = pmax[(size_t)i * NT + tid];
        int   bj = pidx[(size_t)i * NT + tid];
        #pragma unroll
        for (int m = 1; m <= 32; m <<= 1) {
            const float ov = __shfl_xor(bv, m, 64);
            const int   oj = __shfl_xor(bj, m, 64);
            if (ov > bv || (ov == bv && oj < bj)) { bv = ov; bj = oj; }
        }
        if (tid == 0) s_neg = bj;
    }
    __syncthreads();
    const int neg = s_neg;

    const int* xi = xq + (size_t)i * 512;
    const int* xn = xq + (size_t)neg * 512;
    float san = 0.f;
    #pragma unroll
    for (int c = tid; c < 512; c += 256) {
        const int a = xi[c], b = xn[c];
        const f32x2 alo = __builtin_amdgcn_cvt_pk_f32_fp8(a, false);
        const f32x2 ahi = __builtin_amdgcn_cvt_pk_f32_fp8(a, true);
        const f32x2 blo = __builtin_amdgcn_cvt_pk_f32_fp8(b, false);
        const f32x2 bhi = __builtin_amdgcn_cvt_pk_f32_fp8(b, true);
        san += fabsf(alo[0] - blo[0]) + fabsf(alo[1] - blo[1])
             + fabsf(ahi[0] - bhi[0]) + fabsf(ahi[1] - bhi[1]);
    }
    #pragma unroll
    for (int m = 1; m <= 32; m <<= 1) san += __shfl_xor(san, m, 64);
    const int lane = tid & 63, wave = tid >> 6;
    if (lane == 0) red[wave] = san;
    __syncthreads();
    if (tid == 0) {
        const float d_an = (red[0] + red[1] + red[2] + red[3]) / (float)D;
        term[i] = 0.125f * d_ap[i] / (d_an + 1e-7f);
    }
}

// Kernel 4: single-block sum of the 8192 per-row terms -> scalar out.
__global__ __launch_bounds__(256) void sum_kernel(
    const float* __restrict__ term, float* __restrict__ out) {
    const int tid = threadIdx.x;
    float s = 0.f;
    for (int i = tid; i < N; i += 256) s += term[i];
    #pragma unroll
    for (int m = 1; m <= 32; m <<= 1) s += __shfl_xor(s, m, 64);
    __shared__ float red[4];
    const int lane = tid & 63, wave = tid >> 6;
    if (lane == 0) red[wave] = s;
    __syncthreads();
    if (tid == 0) out[0] = red[0] + red[1] + red[2] + red[3];
}

extern "C" void kernel_launch(void* const* d_in, const int* in_sizes, int n_in,
                              void* d_out, int out_size, void* d_ws, size_t ws_size,
                              hipStream_t stream) {
    const float* x = (const float*)d_in[0];
    float* out = (float*)d_out;
    char* ws = (char*)d_ws;

    // Workspace layout (~20.1 MB):
    char* xq    = ws;                                               // 16 MB fp8
    float* pmax = (float*)(ws + (size_t)N * D);                     //  2 MB
    int*   pidx = (int*)((char*)pmax + (size_t)N * NT * 4);         //  2 MB
    float* dap  = (float*)((char*)pidx + (size_t)N * NT * 4);       // 32 KB
    float* term = dap + N;                                          // 32 KB

    chunk_kernel<<<N / CS, 256, 0, stream>>>(x, (int*)xq, dap);
    gemm_argmax_kernel<<<NT * (NT + 1) / 2, 256, 0, stream>>>(xq, pmax, pidx);
    neg_kernel<<<N, 256, 0, stream>>>((const int*)xq, dap, pmax, pidx, term);
    sum_kernel<<<1, 256, 0, stream>>>(term, out);
}